// Round 11
// baseline (420.264 us; speedup 1.0000x reference)
//
#include <hip/hip_runtime.h>

#define NN 20000   // nodes per graph

typedef __attribute__((ext_vector_type(8))) __bf16 bf16x8;
typedef __attribute__((ext_vector_type(8))) unsigned short ushort8;
typedef __attribute__((ext_vector_type(4))) float f32x4;

__device__ __forceinline__ unsigned short f2bf(float f) {
    unsigned u = __builtin_bit_cast(unsigned, f);
    u += 0x7fff + ((u >> 16) & 1);   // round-to-nearest-even
    return (unsigned short)(u >> 16);
}
__device__ __forceinline__ float bf2f(unsigned short h) {
    unsigned u = ((unsigned)h) << 16;
    return __builtin_bit_cast(float, u);
}

// ---------------- fp32 -> bf16 streaming convert ----------------

__global__ void k_tobf(const float* __restrict__ in, unsigned short* __restrict__ outp,
                       long n8) {
    long i = (long)blockIdx.x * 256 + threadIdx.x;
    if (i >= n8) return;
    const float4* s = (const float4*)(in + i * 8);
    float4 v0 = s[0], v1 = s[1];
    ushort8 r;
    r[0] = f2bf(v0.x); r[1] = f2bf(v0.y); r[2] = f2bf(v0.z); r[3] = f2bf(v0.w);
    r[4] = f2bf(v1.x); r[5] = f2bf(v1.y); r[6] = f2bf(v1.z); r[7] = f2bf(v1.w);
    *(ushort8*)(outp + i * 8) = r;
}

// ---------------- CSR build (XCD-affine: batch = (gid&7)%nb) ----------------

__global__ void k_count(const int* __restrict__ dst, long dst_bs,
                        int* __restrict__ counts, long cnt_bs, int E, int nb, int jpb) {
    int gid = blockIdx.x;
    int xcd = gid & 7;
    int b = xcd % nb;
    int xg = 8 / nb;
    int jj = (gid >> 3) * xg + (xcd / nb);
    if (jj >= jpb) return;
    int e = jj * 256 + threadIdx.x;
    if (e < E)
        atomicAdd(&counts[(size_t)b * cnt_bs + dst[(size_t)b * dst_bs + e]], 1);
}

// one 1024-thread block per batch: exclusive scan of counts -> offs, cursor
__global__ void k_scan(const int* __restrict__ counts, long cnt_bs,
                       int* __restrict__ offs, long off_bs,
                       int* __restrict__ cursor, long cur_bs, int n) {
    int b = blockIdx.z;
    const int* cnt = counts + (size_t)b * cnt_bs;
    int* off = offs + (size_t)b * off_bs;
    int* cur = cursor + (size_t)b * cur_bs;
    __shared__ int sums[1024];
    int t = threadIdx.x;
    int chunk = (n + 1023) / 1024;
    int lo = t * chunk;
    int hi = min(lo + chunk, n);
    int s = 0;
    for (int i = lo; i < hi; i++) s += cnt[i];
    sums[t] = s;
    __syncthreads();
    for (int d2 = 1; d2 < 1024; d2 <<= 1) {
        int x = (t >= d2) ? sums[t - d2] : 0;
        __syncthreads();
        sums[t] += x;
        __syncthreads();
    }
    if (t == 1023) off[n] = sums[1023];
    int run = sums[t] - s;
    for (int i = lo; i < hi; i++) {
        int c = cnt[i];
        off[i] = run;
        cur[i] = run;
        run += c;
    }
}

__global__ void k_fill(const int* __restrict__ src, long src_bs,
                       const int* __restrict__ dst, long dst_bs,
                       int* __restrict__ cursor, long cur_bs,
                       unsigned short* __restrict__ elist, long el_bs,
                       int E, int nb, int jpb) {
    int gid = blockIdx.x;
    int xcd = gid & 7;
    int b = xcd % nb;
    int xg = 8 / nb;
    int jj = (gid >> 3) * xg + (xcd / nb);
    if (jj >= jpb) return;
    int e = jj * 256 + threadIdx.x;
    if (e < E) {
        int d = dst[(size_t)b * dst_bs + e];
        int s = src[(size_t)b * src_bs + e];
        int p = atomicAdd(&cursor[(size_t)b * cur_bs + d], 1);
        elist[(size_t)b * el_bs + p] = (unsigned short)s;
    }
}

// ---------------- bf16 aggregation: 64-col strips, XCD-affine batches ----------------

template <bool SPLIT>
__global__ void k_agg(const unsigned short* __restrict__ feat, long feat_bs,
                      const int* __restrict__ offs, long off_bs,
                      const unsigned short* __restrict__ elist, long el_bs,
                      const float* __restrict__ bias,   // nullable
                      void* __restrict__ o1, void* __restrict__ o2,
                      long out_bs, int N, int nb, int nbx) {
    int gid = blockIdx.x;
    int xcd = gid & 7;
    int b = xcd % nb;
    int xg = 8 / nb;
    int jj = (gid >> 3) * xg + (xcd / nb);
    if (jj >= 2 * nbx) return;
    int pass = (jj >= nbx) ? 1 : 0;
    int nbk = jj - pass * nbx;
    int g = threadIdx.x >> 3;        // 32 node-groups per block
    int lane = threadIdx.x & 7;
    int n = nbk * 32 + g;
    if (n >= N) return;
    int col0 = pass * 64 + lane * 8;
    const unsigned short* fp = feat + (size_t)b * feat_bs + col0;
    const int* off = offs + (size_t)b * off_bs;
    const unsigned short* el = elist + (size_t)b * el_bs;
    int lo = off[n], hi = off[n + 1];
    float a0[8] = {}, a1[8] = {}, a2[8] = {}, a3[8] = {};
    auto acc = [&](float* a, ushort8 v) {
#pragma unroll
        for (int i = 0; i < 8; i++) a[i] += bf2f(v[i]);
    };
    int e = lo;
    for (; e < hi && (e & 3); e++)
        acc(a0, *(const ushort8*)&fp[(size_t)el[e] * 128]);
    for (; e + 4 <= hi; e += 4) {
        ushort4 idx = *(const ushort4*)&el[e];
        ushort8 v0 = *(const ushort8*)&fp[(size_t)idx.x * 128];
        ushort8 v1 = *(const ushort8*)&fp[(size_t)idx.y * 128];
        ushort8 v2 = *(const ushort8*)&fp[(size_t)idx.z * 128];
        ushort8 v3 = *(const ushort8*)&fp[(size_t)idx.w * 128];
        acc(a0, v0); acc(a1, v1); acc(a2, v2); acc(a3, v3);
    }
    for (; e < hi; e++)
        acc(a0, *(const ushort8*)&fp[(size_t)el[e] * 128]);
    float r[8];
#pragma unroll
    for (int i = 0; i < 8; i++) r[i] = (a0[i] + a1[i]) + (a2[i] + a3[i]);
    size_t oi = (size_t)b * out_bs + (size_t)n * 128 + col0;
    if (SPLIT) {
        ushort8 qh, ql;
#pragma unroll
        for (int i = 0; i < 8; i++) {
            qh[i] = f2bf(r[i]);
            ql[i] = f2bf(r[i] - bf2f(qh[i]));
        }
        *(ushort8*)((unsigned short*)o1 + oi) = qh;
        *(ushort8*)((unsigned short*)o2 + oi) = ql;
    } else {
        float* op = (float*)o1 + oi;
        const float* bp = bias + col0;
#pragma unroll
        for (int i = 0; i < 8; i++) r[i] += bp[i];
        *(float4*)(op) = make_float4(r[0], r[1], r[2], r[3]);
        *(float4*)(op + 4) = make_float4(r[4], r[5], r[6], r[7]);
    }
}

// ---------------- W prep: fp32 [K][N] -> transposed split bf16 [N][K] ----------------

__global__ void k_prep_w(const float* __restrict__ W1, const float* __restrict__ W2,
                         unsigned short* __restrict__ Wt1h, unsigned short* __restrict__ Wt1l,
                         unsigned short* __restrict__ Wt2h, unsigned short* __restrict__ Wt2l) {
    int i = blockIdx.x * 256 + threadIdx.x;
    if (i < 128 * 256) {
        {   // W1 [128][256] -> Wt1 [256][128]
            int k = i / 256, n = i % 256;
            float v = W1[i];
            unsigned short h = f2bf(v);
            Wt1h[n * 128 + k] = h;
            Wt1l[n * 128 + k] = f2bf(v - bf2f(h));
        }
        {   // W2 [256][128] -> Wt2 [128][256]
            int k = i / 128, n = i % 128;
            float v = W2[i];
            unsigned short h = f2bf(v);
            Wt2h[n * 256 + k] = h;
            Wt2l[n * 256 + k] = f2bf(v - bf2f(h));
        }
    }
}

// ---------------- split-bf16 MFMA GEMM, BM=64*MF, 4 blocks/CU ----------------
// OUT_MODE: 1 = split bf16 (hi/lo), 2 = single bf16. LDS-staged coalesced epilogue,
// ((rl&7)<<2) XOR swizzle (2-way max on store and uint4 readback).

template <int KSTEPS, int NFRAG, int KCHUNKS, int MF, bool RELU, int OUT_MODE, bool DBUF>
__launch_bounds__(256, 4)
__global__ void k_lin(const unsigned short* __restrict__ Ah,
                      const unsigned short* __restrict__ Al, long A_bs,
                      const unsigned short* __restrict__ Wth,
                      const unsigned short* __restrict__ Wtl,
                      const float* __restrict__ bias,   // nullable
                      void* __restrict__ C1, void* __restrict__ C2, long C_bs,
                      int M, int ncTot) {
    constexpr int K = KSTEPS * 32 * KCHUNKS;
    constexpr int WPR = NFRAG * 8;           // LDS words per row of the col-slice
    constexpr int BM = 64 * MF;
    __shared__ unsigned int ldsH[BM * WPR];
    __shared__ unsigned int ldsL[(OUT_MODE == 1) ? BM * WPR : 4];
    int b = blockIdx.z;
    int woff = blockIdx.y * (NFRAG * 16);
    int w = threadIdx.x >> 6, lane = threadIdx.x & 63;
    int colg = lane & 15, kg = lane >> 4;
    int rbase = blockIdx.x * BM + w * (16 * MF);

    int rowm[MF];
    bool okm[MF];
    const unsigned short *pah[MF], *pal[MF];
#pragma unroll
    for (int mf = 0; mf < MF; mf++) {
        rowm[mf] = rbase + mf * 16 + colg;
        okm[mf] = rowm[mf] < M;
        int rc = okm[mf] ? rowm[mf] : M - 1;
        pah[mf] = Ah + (size_t)b * A_bs + (size_t)rc * K + kg * 8;
        pal[mf] = Al + (size_t)b * A_bs + (size_t)rc * K + kg * 8;
    }

    bf16x8 fah[MF][KSTEPS], fal[MF][KSTEPS];
    bf16x8 whA[KSTEPS], wlA[KSTEPS], whB[KSTEPS], wlB[KSTEPS];
    constexpr int NACC = (KCHUNKS > 1) ? NFRAG : 1;
    f32x4 acc[NACC][MF];
#pragma unroll
    for (int i = 0; i < NACC; i++)
#pragma unroll
        for (int mf = 0; mf < MF; mf++) acc[i][mf] = (f32x4){0.f, 0.f, 0.f, 0.f};

    auto loadW = [&](bf16x8* wh, bf16x8* wl, int nf, int kc) {
        const unsigned short* ph = Wth + (size_t)(woff + nf * 16 + colg) * K + kc * (KSTEPS * 32) + kg * 8;
        const unsigned short* pl = Wtl + (size_t)(woff + nf * 16 + colg) * K + kc * (KSTEPS * 32) + kg * 8;
#pragma unroll
        for (int ks = 0; ks < KSTEPS; ks++) {
            wh[ks] = *(const bf16x8*)(ph + ks * 32);
            wl[ks] = *(const bf16x8*)(pl + ks * 32);
        }
    };
    auto mm = [&](bf16x8* wh, bf16x8* wl, f32x4* c) {
#pragma unroll
        for (int ks = 0; ks < KSTEPS; ks++) {
#pragma unroll
            for (int mf = 0; mf < MF; mf++)
                c[mf] = __builtin_amdgcn_mfma_f32_16x16x32_bf16(wh[ks], fah[mf][ks], c[mf], 0, 0, 0);
#pragma unroll
            for (int mf = 0; mf < MF; mf++)
                c[mf] = __builtin_amdgcn_mfma_f32_16x16x32_bf16(wl[ks], fah[mf][ks], c[mf], 0, 0, 0);
#pragma unroll
            for (int mf = 0; mf < MF; mf++)
                c[mf] = __builtin_amdgcn_mfma_f32_16x16x32_bf16(wh[ks], fal[mf][ks], c[mf], 0, 0, 0);
        }
    };
    // epilogue -> LDS (swizzled), per nf & mf
    auto epi = [&](f32x4 a, int nf, int mf) {
        int rl = w * (16 * MF) + mf * 16 + colg;   // row within block tile
        int c0 = woff + nf * 16 + kg * 4;
        float v[4] = {a[0], a[1], a[2], a[3]};
        if (bias) {
            float4 bv = *(const float4*)&bias[c0];
            v[0] += bv.x; v[1] += bv.y; v[2] += bv.z; v[3] += bv.w;
        }
        if (RELU) {
#pragma unroll
            for (int j = 0; j < 4; j++) v[j] = fmaxf(v[j], 0.f);
        }
        int wc = nf * 8 + kg * 2;
        int wcs = wc ^ (((rl & 7) << 2) & (WPR - 1));   // 2-way max, uint2-contiguous
        union { unsigned short u[4]; unsigned int q[2]; } qh, ql;
#pragma unroll
        for (int j = 0; j < 4; j++) {
            qh.u[j] = f2bf(v[j]);
            if (OUT_MODE == 1) ql.u[j] = f2bf(v[j] - bf2f(qh.u[j]));
        }
        ldsH[rl * WPR + wcs] = qh.q[0];
        ldsH[rl * WPR + wcs + 1] = qh.q[1];
        if (OUT_MODE == 1) {
            ldsL[rl * WPR + wcs] = ql.q[0];
            ldsL[rl * WPR + wcs + 1] = ql.q[1];
        }
    };
    auto step = [&](bf16x8* wh, bf16x8* wl, int nf) {
        if constexpr (KCHUNKS > 1) {
            mm(wh, wl, acc[nf]);
        } else {
            f32x4 a[MF];
#pragma unroll
            for (int mf = 0; mf < MF; mf++) a[mf] = (f32x4){0.f, 0.f, 0.f, 0.f};
            mm(wh, wl, a);
#pragma unroll
            for (int mf = 0; mf < MF; mf++) epi(a[mf], nf, mf);
        }
    };

#pragma unroll
    for (int kc = 0; kc < KCHUNKS; kc++) {
#pragma unroll
        for (int ks = 0; ks < KSTEPS; ks++)
#pragma unroll
            for (int mf = 0; mf < MF; mf++) {
                fah[mf][ks] = *(const bf16x8*)(pah[mf] + kc * (KSTEPS * 32) + ks * 32);
                fal[mf][ks] = *(const bf16x8*)(pal[mf] + kc * (KSTEPS * 32) + ks * 32);
            }
        if constexpr (DBUF) {
            loadW(whA, wlA, 0, kc);
#pragma unroll
            for (int nf = 0; nf < NFRAG; nf += 2) {
                loadW(whB, wlB, nf + 1, kc);
                step(whA, wlA, nf);
                if (nf + 2 < NFRAG) loadW(whA, wlA, nf + 2, kc);
                step(whB, wlB, nf + 1);
            }
        } else {
#pragma unroll
            for (int nf = 0; nf < NFRAG; nf++) {
                loadW(whA, wlA, nf, kc);
                step(whA, wlA, nf);
            }
        }
    }
    if constexpr (KCHUNKS > 1) {
#pragma unroll
        for (int nf = 0; nf < NFRAG; nf++)
#pragma unroll
            for (int mf = 0; mf < MF; mf++) epi(acc[nf][mf], nf, mf);
    }

    // coalesced writeback
    __syncthreads();
    constexpr int U4PR = WPR / 4;            // uint4 per row
    constexpr int NU4 = BM * U4PR;
    int t = threadIdx.x;
    int rblk = blockIdx.x * BM;
#pragma unroll
    for (int i = 0; i < NU4 / 256; i++) {
        int idx = t + 256 * i;
        int row = idx / U4PR;
        int wc4 = (idx % U4PR) * 4;
        int swz = wc4 ^ (((row & 7) << 2) & (WPR - 1));
        int grow = rblk + row;
        if (grow < M) {
            size_t ci = (size_t)b * C_bs + (size_t)grow * ncTot + woff + wc4 * 2;
            uint4 v = *(const uint4*)&ldsH[row * WPR + swz];
            *(uint4*)((unsigned short*)C1 + ci) = v;
            if constexpr (OUT_MODE == 1) {
                uint4 v2 = *(const uint4*)&ldsL[row * WPR + swz];
                *(uint4*)((unsigned short*)C2 + ci) = v2;
            }
        }
    }
}

// ---------------- host ----------------

extern "C" void kernel_launch(void* const* d_in, const int* in_sizes, int n_in,
                              void* d_out, int out_size, void* d_ws, size_t ws_size,
                              hipStream_t stream) {
    const float* features = (const float*)d_in[0];  // [B,N,128]
    const int* src = (const int*)d_in[1];           // [B,E]
    const int* dst = (const int*)d_in[2];           // [B,E]
    const float* W1 = (const float*)d_in[3];        // [128,256]
    const float* b1 = (const float*)d_in[4];        // [256]
    const float* W2 = (const float*)d_in[5];        // [256,128]
    const float* b2 = (const float*)d_in[6];        // [128]
    float* out = (float*)d_out;                     // [B,N,128]

    const int B = 4;
    const int N = NN;
    const int E = in_sizes[1] / B;

    auto need = [&](int nb) -> size_t {
        size_t bf = ((size_t)nb * N * (128 + 128 * 2 + 256 * 2 + 128)) * sizeof(unsigned short);
        size_t wt = 4 * 32768 * sizeof(unsigned short);
        size_t ints = (size_t)nb * ((size_t)(N + 1) + N) * sizeof(int)
                    + (size_t)nb * E * sizeof(unsigned short);
        return bf + wt + ints + 256;
    };
    int nb = (ws_size >= need(4)) ? 4 : 1;
    int npass = B / nb;
    int xg = 8 / nb;

    char* p = (char*)d_ws;
    unsigned short* fb  = (unsigned short*)p; p += (size_t)nb * N * 128 * sizeof(unsigned short);
    unsigned short* A1h = (unsigned short*)p; p += (size_t)nb * N * 128 * sizeof(unsigned short);
    unsigned short* A1l = (unsigned short*)p; p += (size_t)nb * N * 128 * sizeof(unsigned short);
    unsigned short* Hh  = (unsigned short*)p; p += (size_t)nb * N * 256 * sizeof(unsigned short);
    unsigned short* Hl  = (unsigned short*)p; p += (size_t)nb * N * 256 * sizeof(unsigned short);
    unsigned short* H2b = (unsigned short*)p; p += (size_t)nb * N * 128 * sizeof(unsigned short);
    unsigned short* Wt1h = (unsigned short*)p; p += 32768 * sizeof(unsigned short);
    unsigned short* Wt1l = (unsigned short*)p; p += 32768 * sizeof(unsigned short);
    unsigned short* Wt2h = (unsigned short*)p; p += 32768 * sizeof(unsigned short);
    unsigned short* Wt2l = (unsigned short*)p; p += 32768 * sizeof(unsigned short);
    int* offs = (int*)p;  p += (size_t)nb * (N + 1) * sizeof(int);
    int* curs = (int*)p;  p += (size_t)nb * N * sizeof(int);
    unsigned short* elist = (unsigned short*)p;

    k_prep_w<<<128, 256, 0, stream>>>(W1, W2, Wt1h, Wt1l, Wt2h, Wt2l);

    const int nbx = (N + 31) / 32;                 // node-blocks per pass
    const int jpbE = (E + 255) / 256;              // edge chunks per batch
    dim3 gEdge(8 * ((jpbE + xg - 1) / xg), 1, 1);
    dim3 gAgg(8 * ((2 * nbx + xg - 1) / xg), 1, 1);

    for (int pass = 0; pass < npass; pass++) {
        int b0 = pass * nb;
        const float* feat_p = features + (size_t)b0 * N * 128;
        const int* src_p = src + (size_t)b0 * E;
        const int* dst_p = dst + (size_t)b0 * E;
        float* out_p = out + (size_t)b0 * N * 128;

        hipMemsetAsync(curs, 0, (size_t)nb * N * sizeof(int), stream);

        // features -> bf16 (streaming)
        long n8 = (long)nb * N * 128 / 8;
        k_tobf<<<(int)((n8 + 255) / 256), 256, 0, stream>>>(feat_p, fb, n8);

        k_count<<<gEdge, 256, 0, stream>>>(dst_p, E, curs, N, E, nb, jpbE);
        k_scan<<<dim3(1, 1, nb), 1024, 0, stream>>>(curs, N, offs, N + 1, curs, N, N);
        k_fill<<<gEdge, 256, 0, stream>>>(src_p, E, dst_p, E, curs, N, elist, E, E, nb, jpbE);

        // conv1 aggregation (bf16 gather) -> split bf16 (A1h, A1l)
        k_agg<true><<<gAgg, 256, 0, stream>>>(fb, (long)N * 128, offs, N + 1,
                                              elist, E, nullptr, A1h, A1l, (long)N * 128,
                                              N, nb, nbx);
        // conv1 linear + bias + relu -> split bf16 (Hh, Hl); y splits 256 cols in 2
        k_lin<4, 8, 1, 1, true, 1, true><<<dim3((N + 63) / 64, 2, nb), 256, 0, stream>>>(
            A1h, A1l, (long)N * 128, Wt1h, Wt1l, b1, Hh, Hl, (long)N * 256, N, 256);
        // conv2 linear (agg commutes): H2b = bf16(H @ W2); y splits 128 cols in 2
        k_lin<4, 4, 2, 1, false, 2, true><<<dim3((N + 63) / 64, 2, nb), 256, 0, stream>>>(
            Hh, Hl, (long)N * 256, Wt2h, Wt2l, nullptr, H2b, nullptr, (long)N * 128, N, 128);
        // conv2 aggregation (bf16 gather) + bias: out = segsum(H2b[src] -> dst) + b2
        k_agg<false><<<gAgg, 256, 0, stream>>>(H2b, (long)N * 128, offs, N + 1,
                                               elist, E, b2, out_p, nullptr, (long)N * 128,
                                               N, nb, nbx);
    }
}

// Round 12
// 384.162 us; speedup vs baseline: 1.0940x; 1.0940x over previous
//
#include <hip/hip_runtime.h>

#define NN 20000   // nodes per graph

typedef __attribute__((ext_vector_type(8))) __bf16 bf16x8;
typedef __attribute__((ext_vector_type(8))) unsigned short ushort8;
typedef __attribute__((ext_vector_type(4))) float f32x4;

__device__ __forceinline__ unsigned short f2bf(float f) {
    unsigned u = __builtin_bit_cast(unsigned, f);
    u += 0x7fff + ((u >> 16) & 1);   // round-to-nearest-even
    return (unsigned short)(u >> 16);
}
__device__ __forceinline__ float bf2f(unsigned short h) {
    unsigned u = ((unsigned)h) << 16;
    return __builtin_bit_cast(float, u);
}

// ---------------- fp32 -> bf16 streaming convert ----------------

__global__ void k_tobf(const float* __restrict__ in, unsigned short* __restrict__ outp,
                       long n8) {
    long i = (long)blockIdx.x * 256 + threadIdx.x;
    if (i >= n8) return;
    const float4* s = (const float4*)(in + i * 8);
    float4 v0 = s[0], v1 = s[1];
    ushort8 r;
    r[0] = f2bf(v0.x); r[1] = f2bf(v0.y); r[2] = f2bf(v0.z); r[3] = f2bf(v0.w);
    r[4] = f2bf(v1.x); r[5] = f2bf(v1.y); r[6] = f2bf(v1.z); r[7] = f2bf(v1.w);
    *(ushort8*)(outp + i * 8) = r;
}

// ---------------- CSR build (XCD-affine: batch = (gid&7)%nb) ----------------

__global__ void k_count(const int* __restrict__ dst, long dst_bs,
                        int* __restrict__ counts, long cnt_bs, int E, int nb, int jpb) {
    int gid = blockIdx.x;
    int xcd = gid & 7;
    int b = xcd % nb;
    int xg = 8 / nb;
    int jj = (gid >> 3) * xg + (xcd / nb);
    if (jj >= jpb) return;
    int e = jj * 256 + threadIdx.x;
    if (e < E)
        atomicAdd(&counts[(size_t)b * cnt_bs + dst[(size_t)b * dst_bs + e]], 1);
}

// one 1024-thread block per batch: exclusive scan of counts -> offs, cursor
__global__ void k_scan(const int* __restrict__ counts, long cnt_bs,
                       int* __restrict__ offs, long off_bs,
                       int* __restrict__ cursor, long cur_bs, int n) {
    int b = blockIdx.z;
    const int* cnt = counts + (size_t)b * cnt_bs;
    int* off = offs + (size_t)b * off_bs;
    int* cur = cursor + (size_t)b * cur_bs;
    __shared__ int sums[1024];
    int t = threadIdx.x;
    int chunk = (n + 1023) / 1024;
    int lo = t * chunk;
    int hi = min(lo + chunk, n);
    int s = 0;
    for (int i = lo; i < hi; i++) s += cnt[i];
    sums[t] = s;
    __syncthreads();
    for (int d2 = 1; d2 < 1024; d2 <<= 1) {
        int x = (t >= d2) ? sums[t - d2] : 0;
        __syncthreads();
        sums[t] += x;
        __syncthreads();
    }
    if (t == 1023) off[n] = sums[1023];
    int run = sums[t] - s;
    for (int i = lo; i < hi; i++) {
        int c = cnt[i];
        off[i] = run;
        cur[i] = run;
        run += c;
    }
}

__global__ void k_fill(const int* __restrict__ src, long src_bs,
                       const int* __restrict__ dst, long dst_bs,
                       int* __restrict__ cursor, long cur_bs,
                       unsigned short* __restrict__ elist, long el_bs,
                       int E, int nb, int jpb) {
    int gid = blockIdx.x;
    int xcd = gid & 7;
    int b = xcd % nb;
    int xg = 8 / nb;
    int jj = (gid >> 3) * xg + (xcd / nb);
    if (jj >= jpb) return;
    int e = jj * 256 + threadIdx.x;
    if (e < E) {
        int d = dst[(size_t)b * dst_bs + e];
        int s = src[(size_t)b * src_bs + e];
        int p = atomicAdd(&cursor[(size_t)b * cur_bs + d], 1);
        elist[(size_t)b * el_bs + p] = (unsigned short)s;
    }
}

// ---------------- bf16 aggregation: 64-col strips, XCD-affine batches ----------------

template <bool SPLIT>
__global__ void k_agg(const unsigned short* __restrict__ feat, long feat_bs,
                      const int* __restrict__ offs, long off_bs,
                      const unsigned short* __restrict__ elist, long el_bs,
                      const float* __restrict__ bias,   // nullable
                      void* __restrict__ o1, void* __restrict__ o2,
                      long out_bs, int N, int nb, int nbx) {
    int gid = blockIdx.x;
    int xcd = gid & 7;
    int b = xcd % nb;
    int xg = 8 / nb;
    int jj = (gid >> 3) * xg + (xcd / nb);
    if (jj >= 2 * nbx) return;
    int pass = (jj >= nbx) ? 1 : 0;
    int nbk = jj - pass * nbx;
    int g = threadIdx.x >> 3;        // 32 node-groups per block
    int lane = threadIdx.x & 7;
    int n = nbk * 32 + g;
    if (n >= N) return;
    int col0 = pass * 64 + lane * 8;
    const unsigned short* fp = feat + (size_t)b * feat_bs + col0;
    const int* off = offs + (size_t)b * off_bs;
    const unsigned short* el = elist + (size_t)b * el_bs;
    int lo = off[n], hi = off[n + 1];
    float a0[8] = {}, a1[8] = {}, a2[8] = {}, a3[8] = {};
    auto acc = [&](float* a, ushort8 v) {
#pragma unroll
        for (int i = 0; i < 8; i++) a[i] += bf2f(v[i]);
    };
    int e = lo;
    for (; e < hi && (e & 3); e++)
        acc(a0, *(const ushort8*)&fp[(size_t)el[e] * 128]);
    for (; e + 4 <= hi; e += 4) {
        ushort4 idx = *(const ushort4*)&el[e];
        ushort8 v0 = *(const ushort8*)&fp[(size_t)idx.x * 128];
        ushort8 v1 = *(const ushort8*)&fp[(size_t)idx.y * 128];
        ushort8 v2 = *(const ushort8*)&fp[(size_t)idx.z * 128];
        ushort8 v3 = *(const ushort8*)&fp[(size_t)idx.w * 128];
        acc(a0, v0); acc(a1, v1); acc(a2, v2); acc(a3, v3);
    }
    for (; e < hi; e++)
        acc(a0, *(const ushort8*)&fp[(size_t)el[e] * 128]);
    float r[8];
#pragma unroll
    for (int i = 0; i < 8; i++) r[i] = (a0[i] + a1[i]) + (a2[i] + a3[i]);
    size_t oi = (size_t)b * out_bs + (size_t)n * 128 + col0;
    if (SPLIT) {
        ushort8 qh, ql;
#pragma unroll
        for (int i = 0; i < 8; i++) {
            qh[i] = f2bf(r[i]);
            ql[i] = f2bf(r[i] - bf2f(qh[i]));
        }
        *(ushort8*)((unsigned short*)o1 + oi) = qh;
        *(ushort8*)((unsigned short*)o2 + oi) = ql;
    } else {
        float* op = (float*)o1 + oi;
        const float* bp = bias + col0;
#pragma unroll
        for (int i = 0; i < 8; i++) r[i] += bp[i];
        *(float4*)(op) = make_float4(r[0], r[1], r[2], r[3]);
        *(float4*)(op + 4) = make_float4(r[4], r[5], r[6], r[7]);
    }
}

// ---------------- W prep: fp32 [K][N] -> transposed split bf16 [N][K] ----------------

__global__ void k_prep_w(const float* __restrict__ W1, const float* __restrict__ W2,
                         unsigned short* __restrict__ Wt1h, unsigned short* __restrict__ Wt1l,
                         unsigned short* __restrict__ Wt2h, unsigned short* __restrict__ Wt2l) {
    int i = blockIdx.x * 256 + threadIdx.x;
    if (i < 128 * 256) {
        {   // W1 [128][256] -> Wt1 [256][128]
            int k = i / 256, n = i % 256;
            float v = W1[i];
            unsigned short h = f2bf(v);
            Wt1h[n * 128 + k] = h;
            Wt1l[n * 128 + k] = f2bf(v - bf2f(h));
        }
        {   // W2 [256][128] -> Wt2 [128][256]
            int k = i / 128, n = i % 128;
            float v = W2[i];
            unsigned short h = f2bf(v);
            Wt2h[n * 256 + k] = h;
            Wt2l[n * 256 + k] = f2bf(v - bf2f(h));
        }
    }
}

// ---------------- FUSED MLP: H2 = bf16( relu(A1@W1+b1) @ W2 ), split-bf16 MFMA ------
// 64-row tile, 4 waves x 16 rows. H intermediate lives only in a per-wave LDS slab
// (computed in two 128-col halves). No barriers: each wave writes & reads only its
// own 16 rows. acc2 persists over both K2 halves. LDS-staged coalesced H2 writeback.

__launch_bounds__(256, 3)
__global__ void k_mlp(const unsigned short* __restrict__ A1h,
                      const unsigned short* __restrict__ A1l, long A_bs,
                      const unsigned short* __restrict__ Wt1h,
                      const unsigned short* __restrict__ Wt1l,
                      const unsigned short* __restrict__ Wt2h,
                      const unsigned short* __restrict__ Wt2l,
                      const float* __restrict__ b1,
                      unsigned short* __restrict__ H2b, long C_bs, int M) {
    __shared__ unsigned short HH[64 * 128];   // 16 KB: hi half-tile (later reused for H2)
    __shared__ unsigned short HL[64 * 128];   // 16 KB: lo half-tile
    char* HHc = (char*)HH;
    char* HLc = (char*)HL;
    int b = blockIdx.z;
    int w = threadIdx.x >> 6, lane = threadIdx.x & 63;
    int colg = lane & 15, kg = lane >> 4;
    int rl = w * 16 + colg;                   // row within block tile (this lane's row)
    int row = blockIdx.x * 64 + rl;           // global row
    int rc = (row < M) ? row : M - 1;
    int swz = (rl & 7) << 4;                  // XOR byte-swizzle per row

    // A1 fragments (K1=128): validated pattern
    const unsigned short* pa_h = A1h + (size_t)b * A_bs + (size_t)rc * 128 + kg * 8;
    const unsigned short* pa_l = A1l + (size_t)b * A_bs + (size_t)rc * 128 + kg * 8;
    bf16x8 fa_h[4], fa_l[4];
#pragma unroll
    for (int ks = 0; ks < 4; ks++) {
        fa_h[ks] = *(const bf16x8*)(pa_h + ks * 32);
        fa_l[ks] = *(const bf16x8*)(pa_l + ks * 32);
    }

    f32x4 acc2[8];
#pragma unroll
    for (int i = 0; i < 8; i++) acc2[i] = (f32x4){0.f, 0.f, 0.f, 0.f};

    auto loadW1 = [&](bf16x8* wh, bf16x8* wl, int c) {
        const unsigned short* ph = Wt1h + (size_t)c * 128 + kg * 8;
        const unsigned short* pl = Wt1l + (size_t)c * 128 + kg * 8;
#pragma unroll
        for (int ks = 0; ks < 4; ks++) {
            wh[ks] = *(const bf16x8*)(ph + ks * 32);
            wl[ks] = *(const bf16x8*)(pl + ks * 32);
        }
    };
    // phase-A epilogue: bias+relu+split -> per-wave LDS half-tile
    auto epiA = [&](f32x4 a, int nf, int kh) {
        int c0 = kh * 128 + nf * 16 + kg * 4;
        float4 bv = *(const float4*)&b1[c0];
        float v[4] = {a[0] + bv.x, a[1] + bv.y, a[2] + bv.z, a[3] + bv.w};
#pragma unroll
        for (int j = 0; j < 4; j++) v[j] = fmaxf(v[j], 0.f);
        union { unsigned short u[4]; uint2 q; } qh, ql;
#pragma unroll
        for (int j = 0; j < 4; j++) {
            qh.u[j] = f2bf(v[j]);
            ql.u[j] = f2bf(v[j] - bf2f(qh.u[j]));
        }
        int off = (rl * 256 + nf * 32 + kg * 8) ^ swz;
        *(uint2*)(HHc + off) = qh.q;
        *(uint2*)(HLc + off) = ql.q;
    };

#pragma unroll
    for (int kh = 0; kh < 2; kh++) {
        // ---- phase A: H cols [kh*128, kh*128+128) -> LDS ----
        bf16x8 whA[4], wlA[4], whB[4], wlB[4];
#pragma unroll
        for (int nf = 0; nf < 8; nf += 2) {
            loadW1(whA, wlA, kh * 128 + nf * 16 + colg);
            loadW1(whB, wlB, kh * 128 + (nf + 1) * 16 + colg);
            f32x4 aA = (f32x4){0.f, 0.f, 0.f, 0.f};
            f32x4 aB = (f32x4){0.f, 0.f, 0.f, 0.f};
#pragma unroll
            for (int ks = 0; ks < 4; ks++) {
                aA = __builtin_amdgcn_mfma_f32_16x16x32_bf16(whA[ks], fa_h[ks], aA, 0, 0, 0);
                aB = __builtin_amdgcn_mfma_f32_16x16x32_bf16(whB[ks], fa_h[ks], aB, 0, 0, 0);
                aA = __builtin_amdgcn_mfma_f32_16x16x32_bf16(wlA[ks], fa_h[ks], aA, 0, 0, 0);
                aB = __builtin_amdgcn_mfma_f32_16x16x32_bf16(wlB[ks], fa_h[ks], aB, 0, 0, 0);
                aA = __builtin_amdgcn_mfma_f32_16x16x32_bf16(whA[ks], fa_l[ks], aA, 0, 0, 0);
                aB = __builtin_amdgcn_mfma_f32_16x16x32_bf16(whB[ks], fa_l[ks], aB, 0, 0, 0);
            }
            epiA(aA, nf, kh);
            epiA(aB, nf + 1, kh);
        }
        // ---- phase B: acc2 += H[:, kh-half] @ W2[kh-half, :] ----
#pragma unroll
        for (int ks2 = 0; ks2 < 4; ks2++) {
            int roff = (rl * 256 + ks2 * 64 + kg * 16) ^ swz;
            bf16x8 fh = *(const bf16x8*)(HHc + roff);
            bf16x8 fl = *(const bf16x8*)(HLc + roff);
            int kb = kh * 128 + ks2 * 32 + kg * 8;
            bf16x8 w2h[8], w2l[8];
#pragma unroll
            for (int nf2 = 0; nf2 < 8; nf2++) {
                w2h[nf2] = *(const bf16x8*)(Wt2h + (size_t)(nf2 * 16 + colg) * 256 + kb);
                w2l[nf2] = *(const bf16x8*)(Wt2l + (size_t)(nf2 * 16 + colg) * 256 + kb);
            }
#pragma unroll
            for (int nf2 = 0; nf2 < 8; nf2++) {
                acc2[nf2] = __builtin_amdgcn_mfma_f32_16x16x32_bf16(w2h[nf2], fh, acc2[nf2], 0, 0, 0);
                acc2[nf2] = __builtin_amdgcn_mfma_f32_16x16x32_bf16(w2l[nf2], fh, acc2[nf2], 0, 0, 0);
                acc2[nf2] = __builtin_amdgcn_mfma_f32_16x16x32_bf16(w2h[nf2], fl, acc2[nf2], 0, 0, 0);
            }
        }
    }

    // ---- epilogue: H2 (bf16) -> LDS (reuse HH) -> coalesced global ----
#pragma unroll
    for (int nf2 = 0; nf2 < 8; nf2++) {
        union { unsigned short u[4]; uint2 q; } qh;
#pragma unroll
        for (int j = 0; j < 4; j++) qh.u[j] = f2bf(acc2[nf2][j]);
        int off = (rl * 256 + nf2 * 32 + kg * 8) ^ swz;
        *(uint2*)(HHc + off) = qh.q;
    }
#pragma unroll
    for (int it = 0; it < 4; it++) {
        int idx = it * 64 + lane;
        int r2 = w * 16 + (idx >> 4);
        int u4 = idx & 15;
        int off = (r2 * 256 + u4 * 16) ^ ((r2 & 7) << 4);
        int grow = blockIdx.x * 64 + r2;
        if (grow < M) {
            uint4 v = *(const uint4*)(HHc + off);
            *(uint4*)(H2b + (size_t)b * C_bs + (size_t)grow * 128 + u4 * 8) = v;
        }
    }
}

// ---------------- host ----------------

extern "C" void kernel_launch(void* const* d_in, const int* in_sizes, int n_in,
                              void* d_out, int out_size, void* d_ws, size_t ws_size,
                              hipStream_t stream) {
    const float* features = (const float*)d_in[0];  // [B,N,128]
    const int* src = (const int*)d_in[1];           // [B,E]
    const int* dst = (const int*)d_in[2];           // [B,E]
    const float* W1 = (const float*)d_in[3];        // [128,256]
    const float* b1 = (const float*)d_in[4];        // [256]
    const float* W2 = (const float*)d_in[5];        // [256,128]
    const float* b2 = (const float*)d_in[6];        // [128]
    float* out = (float*)d_out;                     // [B,N,128]

    const int B = 4;
    const int N = NN;
    const int E = in_sizes[1] / B;

    auto need = [&](int nb) -> size_t {
        size_t bf = ((size_t)nb * N * (128 + 128 * 2 + 128)) * sizeof(unsigned short);
        size_t wt = 4 * 32768 * sizeof(unsigned short);
        size_t ints = (size_t)nb * ((size_t)(N + 1) + N) * sizeof(int)
                    + (size_t)nb * E * sizeof(unsigned short);
        return bf + wt + ints + 256;
    };
    int nb = (ws_size >= need(4)) ? 4 : 1;
    int npass = B / nb;
    int xg = 8 / nb;

    char* p = (char*)d_ws;
    unsigned short* fb  = (unsigned short*)p; p += (size_t)nb * N * 128 * sizeof(unsigned short);
    unsigned short* A1h = (unsigned short*)p; p += (size_t)nb * N * 128 * sizeof(unsigned short);
    unsigned short* A1l = (unsigned short*)p; p += (size_t)nb * N * 128 * sizeof(unsigned short);
    unsigned short* H2b = (unsigned short*)p; p += (size_t)nb * N * 128 * sizeof(unsigned short);
    unsigned short* Wt1h = (unsigned short*)p; p += 32768 * sizeof(unsigned short);
    unsigned short* Wt1l = (unsigned short*)p; p += 32768 * sizeof(unsigned short);
    unsigned short* Wt2h = (unsigned short*)p; p += 32768 * sizeof(unsigned short);
    unsigned short* Wt2l = (unsigned short*)p; p += 32768 * sizeof(unsigned short);
    int* offs = (int*)p;  p += (size_t)nb * (N + 1) * sizeof(int);
    int* curs = (int*)p;  p += (size_t)nb * N * sizeof(int);
    unsigned short* elist = (unsigned short*)p;

    k_prep_w<<<128, 256, 0, stream>>>(W1, W2, Wt1h, Wt1l, Wt2h, Wt2l);

    const int nbx = (N + 31) / 32;                 // node-blocks per pass
    const int jpbE = (E + 255) / 256;              // edge chunks per batch
    dim3 gEdge(8 * ((jpbE + xg - 1) / xg), 1, 1);
    dim3 gAgg(8 * ((2 * nbx + xg - 1) / xg), 1, 1);

    for (int pass = 0; pass < npass; pass++) {
        int b0 = pass * nb;
        const float* feat_p = features + (size_t)b0 * N * 128;
        const int* src_p = src + (size_t)b0 * E;
        const int* dst_p = dst + (size_t)b0 * E;
        float* out_p = out + (size_t)b0 * N * 128;

        hipMemsetAsync(curs, 0, (size_t)nb * N * sizeof(int), stream);

        // features -> bf16 (streaming)
        long n8 = (long)nb * N * 128 / 8;
        k_tobf<<<(int)((n8 + 255) / 256), 256, 0, stream>>>(feat_p, fb, n8);

        k_count<<<gEdge, 256, 0, stream>>>(dst_p, E, curs, N, E, nb, jpbE);
        k_scan<<<dim3(1, 1, nb), 1024, 0, stream>>>(curs, N, offs, N + 1, curs, N, N);
        k_fill<<<gEdge, 256, 0, stream>>>(src_p, E, dst_p, E, curs, N, elist, E, E, nb, jpbE);

        // conv1 aggregation (bf16 gather) -> split bf16 (A1h, A1l)
        k_agg<true><<<gAgg, 256, 0, stream>>>(fb, (long)N * 128, offs, N + 1,
                                              elist, E, nullptr, A1h, A1l, (long)N * 128,
                                              N, nb, nbx);
        // FUSED: H2b = bf16( relu(A1@W1+b1) @ W2 )
        k_mlp<<<dim3((N + 63) / 64, 1, nb), 256, 0, stream>>>(
            A1h, A1l, (long)N * 128, Wt1h, Wt1l, Wt2h, Wt2l, b1,
            H2b, (long)N * 128, N);
        // conv2 aggregation (bf16 gather) + bias: out = segsum(H2b[src] -> dst) + b2
        k_agg<false><<<gAgg, 256, 0, stream>>>(H2b, (long)N * 128, offs, N + 1,
                                               elist, E, b2, out_p, nullptr, (long)N * 128,
                                               N, nb, nbx);
    }
}

// Round 13
// 310.063 us; speedup vs baseline: 1.3554x; 1.2390x over previous
//
#include <hip/hip_runtime.h>

#define NN 20000   // nodes per graph

typedef __attribute__((ext_vector_type(8))) __bf16 bf16x8;
typedef __attribute__((ext_vector_type(8))) unsigned short ushort8;
typedef __attribute__((ext_vector_type(4))) float f32x4;

__device__ __forceinline__ unsigned short f2bf(float f) {
    unsigned u = __builtin_bit_cast(unsigned, f);
    u += 0x7fff + ((u >> 16) & 1);   // round-to-nearest-even
    return (unsigned short)(u >> 16);
}
__device__ __forceinline__ float bf2f(unsigned short h) {
    unsigned u = ((unsigned)h) << 16;
    return __builtin_bit_cast(float, u);
}

// ---------------- fp32 -> bf16 streaming convert ----------------

__global__ void k_tobf(const float* __restrict__ in, unsigned short* __restrict__ outp,
                       long n8) {
    long i = (long)blockIdx.x * 256 + threadIdx.x;
    if (i >= n8) return;
    const float4* s = (const float4*)(in + i * 8);
    float4 v0 = s[0], v1 = s[1];
    ushort8 r;
    r[0] = f2bf(v0.x); r[1] = f2bf(v0.y); r[2] = f2bf(v0.z); r[3] = f2bf(v0.w);
    r[4] = f2bf(v1.x); r[5] = f2bf(v1.y); r[6] = f2bf(v1.z); r[7] = f2bf(v1.w);
    *(ushort8*)(outp + i * 8) = r;
}

// ---------------- CSR build (XCD-affine: batch = (gid&7)%nb) ----------------

__global__ void k_count(const int* __restrict__ dst, long dst_bs,
                        int* __restrict__ counts, long cnt_bs, int E, int nb, int jpb) {
    int gid = blockIdx.x;
    int xcd = gid & 7;
    int b = xcd % nb;
    int xg = 8 / nb;
    int jj = (gid >> 3) * xg + (xcd / nb);
    if (jj >= jpb) return;
    int e = jj * 256 + threadIdx.x;
    if (e < E)
        atomicAdd(&counts[(size_t)b * cnt_bs + dst[(size_t)b * dst_bs + e]], 1);
}

// one 1024-thread block per batch: exclusive scan of counts -> offs, cursor
__global__ void k_scan(const int* __restrict__ counts, long cnt_bs,
                       int* __restrict__ offs, long off_bs,
                       int* __restrict__ cursor, long cur_bs, int n) {
    int b = blockIdx.z;
    const int* cnt = counts + (size_t)b * cnt_bs;
    int* off = offs + (size_t)b * off_bs;
    int* cur = cursor + (size_t)b * cur_bs;
    __shared__ int sums[1024];
    int t = threadIdx.x;
    int chunk = (n + 1023) / 1024;
    int lo = t * chunk;
    int hi = min(lo + chunk, n);
    int s = 0;
    for (int i = lo; i < hi; i++) s += cnt[i];
    sums[t] = s;
    __syncthreads();
    for (int d2 = 1; d2 < 1024; d2 <<= 1) {
        int x = (t >= d2) ? sums[t - d2] : 0;
        __syncthreads();
        sums[t] += x;
        __syncthreads();
    }
    if (t == 1023) off[n] = sums[1023];
    int run = sums[t] - s;
    for (int i = lo; i < hi; i++) {
        int c = cnt[i];
        off[i] = run;
        cur[i] = run;
        run += c;
    }
}

__global__ void k_fill(const int* __restrict__ src, long src_bs,
                       const int* __restrict__ dst, long dst_bs,
                       int* __restrict__ cursor, long cur_bs,
                       unsigned short* __restrict__ elist, long el_bs,
                       int E, int nb, int jpb) {
    int gid = blockIdx.x;
    int xcd = gid & 7;
    int b = xcd % nb;
    int xg = 8 / nb;
    int jj = (gid >> 3) * xg + (xcd / nb);
    if (jj >= jpb) return;
    int e = jj * 256 + threadIdx.x;
    if (e < E) {
        int d = dst[(size_t)b * dst_bs + e];
        int s = src[(size_t)b * src_bs + e];
        int p = atomicAdd(&cursor[(size_t)b * cur_bs + d], 1);
        elist[(size_t)b * el_bs + p] = (unsigned short)s;
    }
}

// ---------------- bf16 aggregation: 64-col strips, XCD-affine batches ----------------
// BFOUT: write single bf16 (no bias); else fp32 + bias.

template <bool BFOUT>
__global__ void k_agg(const unsigned short* __restrict__ feat, long feat_bs,
                      const int* __restrict__ offs, long off_bs,
                      const unsigned short* __restrict__ elist, long el_bs,
                      const float* __restrict__ bias,   // nullable
                      void* __restrict__ o1,
                      long out_bs, int N, int nb, int nbx) {
    int gid = blockIdx.x;
    int xcd = gid & 7;
    int b = xcd % nb;
    int xg = 8 / nb;
    int jj = (gid >> 3) * xg + (xcd / nb);
    if (jj >= 2 * nbx) return;
    int pass = (jj >= nbx) ? 1 : 0;
    int nbk = jj - pass * nbx;
    int g = threadIdx.x >> 3;        // 32 node-groups per block
    int lane = threadIdx.x & 7;
    int n = nbk * 32 + g;
    if (n >= N) return;
    int col0 = pass * 64 + lane * 8;
    const unsigned short* fp = feat + (size_t)b * feat_bs + col0;
    const int* off = offs + (size_t)b * off_bs;
    const unsigned short* el = elist + (size_t)b * el_bs;
    int lo = off[n], hi = off[n + 1];
    float a0[8] = {}, a1[8] = {}, a2[8] = {}, a3[8] = {};
    auto acc = [&](float* a, ushort8 v) {
#pragma unroll
        for (int i = 0; i < 8; i++) a[i] += bf2f(v[i]);
    };
    int e = lo;
    for (; e < hi && (e & 3); e++)
        acc(a0, *(const ushort8*)&fp[(size_t)el[e] * 128]);
    for (; e + 4 <= hi; e += 4) {
        ushort4 idx = *(const ushort4*)&el[e];
        ushort8 v0 = *(const ushort8*)&fp[(size_t)idx.x * 128];
        ushort8 v1 = *(const ushort8*)&fp[(size_t)idx.y * 128];
        ushort8 v2 = *(const ushort8*)&fp[(size_t)idx.z * 128];
        ushort8 v3 = *(const ushort8*)&fp[(size_t)idx.w * 128];
        acc(a0, v0); acc(a1, v1); acc(a2, v2); acc(a3, v3);
    }
    for (; e < hi; e++)
        acc(a0, *(const ushort8*)&fp[(size_t)el[e] * 128]);
    float r[8];
#pragma unroll
    for (int i = 0; i < 8; i++) r[i] = (a0[i] + a1[i]) + (a2[i] + a3[i]);
    size_t oi = (size_t)b * out_bs + (size_t)n * 128 + col0;
    if (BFOUT) {
        ushort8 qh;
#pragma unroll
        for (int i = 0; i < 8; i++) qh[i] = f2bf(r[i]);
        *(ushort8*)((unsigned short*)o1 + oi) = qh;
    } else {
        float* op = (float*)o1 + oi;
        const float* bp = bias + col0;
#pragma unroll
        for (int i = 0; i < 8; i++) r[i] += bp[i];
        *(float4*)(op) = make_float4(r[0], r[1], r[2], r[3]);
        *(float4*)(op + 4) = make_float4(r[4], r[5], r[6], r[7]);
    }
}

// ---------------- W prep: fp32 [K][N] -> transposed bf16 [N][K] ----------------

__global__ void k_prep_w(const float* __restrict__ W1, const float* __restrict__ W2,
                         unsigned short* __restrict__ Wt1, unsigned short* __restrict__ Wt2) {
    int i = blockIdx.x * 256 + threadIdx.x;
    if (i < 128 * 256) {
        {   // W1 [128][256] -> Wt1 [256][128]
            int k = i / 256, n = i % 256;
            Wt1[n * 128 + k] = f2bf(W1[i]);
        }
        {   // W2 [256][128] -> Wt2 [128][256]
            int k = i / 128, n = i % 128;
            Wt2[n * 256 + k] = f2bf(W2[i]);
        }
    }
}

// ---------------- FUSED MLP (pure bf16): H2 = bf16( relu(A1@W1+b1) @ W2 ) ------------
// 64-row tile, 4 waves x 16 rows, no barriers (per-wave-private LDS rows).
// Phase A computes H-cols in two 128-col halves into a 16 KB LDS tile; phase B
// immediately consumes as GEMM2 A-operand; acc2 persists. Coalesced H2 writeback.

__launch_bounds__(256, 4)
__global__ void k_mlp(const unsigned short* __restrict__ A1, long A_bs,
                      const unsigned short* __restrict__ Wt1,
                      const unsigned short* __restrict__ Wt2,
                      const float* __restrict__ b1,
                      unsigned short* __restrict__ H2b, long C_bs, int M) {
    __shared__ unsigned short HH[64 * 128];   // 16 KB half-tile (reused for H2 out)
    char* HHc = (char*)HH;
    int b = blockIdx.z;
    int w = threadIdx.x >> 6, lane = threadIdx.x & 63;
    int colg = lane & 15, kg = lane >> 4;
    int rl = w * 16 + colg;                   // this lane's row within block tile
    int row = blockIdx.x * 64 + rl;
    int rc = (row < M) ? row : M - 1;
    int swz = (rl & 7) << 4;

    const unsigned short* pa = A1 + (size_t)b * A_bs + (size_t)rc * 128 + kg * 8;
    bf16x8 fa[4];
#pragma unroll
    for (int ks = 0; ks < 4; ks++) fa[ks] = *(const bf16x8*)(pa + ks * 32);

    f32x4 acc2[8];
#pragma unroll
    for (int i = 0; i < 8; i++) acc2[i] = (f32x4){0.f, 0.f, 0.f, 0.f};

    auto loadW1 = [&](bf16x8* wh, int c) {
        const unsigned short* ph = Wt1 + (size_t)c * 128 + kg * 8;
#pragma unroll
        for (int ks = 0; ks < 4; ks++) wh[ks] = *(const bf16x8*)(ph + ks * 32);
    };
    auto epiA = [&](f32x4 a, int nf, int kh) {
        int c0 = kh * 128 + nf * 16 + kg * 4;
        float4 bv = *(const float4*)&b1[c0];
        float v[4] = {a[0] + bv.x, a[1] + bv.y, a[2] + bv.z, a[3] + bv.w};
#pragma unroll
        for (int j = 0; j < 4; j++) v[j] = fmaxf(v[j], 0.f);
        union { unsigned short u[4]; uint2 q; } qh;
#pragma unroll
        for (int j = 0; j < 4; j++) qh.u[j] = f2bf(v[j]);
        int off = (rl * 256 + nf * 32 + kg * 8) ^ swz;
        *(uint2*)(HHc + off) = qh.q;
    };

#pragma unroll
    for (int kh = 0; kh < 2; kh++) {
        // ---- phase A: H cols [kh*128, kh*128+128) -> LDS ----
        bf16x8 whA[4], whB[4];
#pragma unroll
        for (int nf = 0; nf < 8; nf += 2) {
            loadW1(whA, kh * 128 + nf * 16 + colg);
            loadW1(whB, kh * 128 + (nf + 1) * 16 + colg);
            f32x4 aA = (f32x4){0.f, 0.f, 0.f, 0.f};
            f32x4 aB = (f32x4){0.f, 0.f, 0.f, 0.f};
#pragma unroll
            for (int ks = 0; ks < 4; ks++) {
                aA = __builtin_amdgcn_mfma_f32_16x16x32_bf16(whA[ks], fa[ks], aA, 0, 0, 0);
                aB = __builtin_amdgcn_mfma_f32_16x16x32_bf16(whB[ks], fa[ks], aB, 0, 0, 0);
            }
            epiA(aA, nf, kh);
            epiA(aB, nf + 1, kh);
        }
        // ---- phase B: acc2 += H[:, kh-half] @ W2[kh-half, :] ----
#pragma unroll
        for (int ks2 = 0; ks2 < 4; ks2++) {
            int roff = (rl * 256 + ks2 * 64 + kg * 16) ^ swz;
            bf16x8 fh = *(const bf16x8*)(HHc + roff);
            int kb = kh * 128 + ks2 * 32 + kg * 8;
            bf16x8 w2[8];
#pragma unroll
            for (int nf2 = 0; nf2 < 8; nf2++)
                w2[nf2] = *(const bf16x8*)(Wt2 + (size_t)(nf2 * 16 + colg) * 256 + kb);
#pragma unroll
            for (int nf2 = 0; nf2 < 8; nf2++)
                acc2[nf2] = __builtin_amdgcn_mfma_f32_16x16x32_bf16(w2[nf2], fh, acc2[nf2], 0, 0, 0);
        }
    }

    // ---- epilogue: H2 (bf16) -> LDS (reuse HH) -> coalesced global ----
#pragma unroll
    for (int nf2 = 0; nf2 < 8; nf2++) {
        union { unsigned short u[4]; uint2 q; } qh;
#pragma unroll
        for (int j = 0; j < 4; j++) qh.u[j] = f2bf(acc2[nf2][j]);
        int off = (rl * 256 + nf2 * 32 + kg * 8) ^ swz;
        *(uint2*)(HHc + off) = qh.q;
    }
#pragma unroll
    for (int it = 0; it < 4; it++) {
        int idx = it * 64 + lane;
        int r2 = w * 16 + (idx >> 4);
        int u4 = idx & 15;
        int off = (r2 * 256 + u4 * 16) ^ ((r2 & 7) << 4);
        int grow = blockIdx.x * 64 + r2;
        if (grow < M) {
            uint4 v = *(const uint4*)(HHc + off);
            *(uint4*)(H2b + (size_t)b * C_bs + (size_t)grow * 128 + u4 * 8) = v;
        }
    }
}

// ---------------- host ----------------

extern "C" void kernel_launch(void* const* d_in, const int* in_sizes, int n_in,
                              void* d_out, int out_size, void* d_ws, size_t ws_size,
                              hipStream_t stream) {
    const float* features = (const float*)d_in[0];  // [B,N,128]
    const int* src = (const int*)d_in[1];           // [B,E]
    const int* dst = (const int*)d_in[2];           // [B,E]
    const float* W1 = (const float*)d_in[3];        // [128,256]
    const float* b1 = (const float*)d_in[4];        // [256]
    const float* W2 = (const float*)d_in[5];        // [256,128]
    const float* b2 = (const float*)d_in[6];        // [128]
    float* out = (float*)d_out;                     // [B,N,128]

    const int B = 4;
    const int N = NN;
    const int E = in_sizes[1] / B;

    auto need = [&](int nb) -> size_t {
        size_t bf = ((size_t)nb * N * (128 + 128 + 128)) * sizeof(unsigned short);
        size_t wt = 2 * 32768 * sizeof(unsigned short);
        size_t ints = (size_t)nb * ((size_t)(N + 1) + N) * sizeof(int)
                    + (size_t)nb * E * sizeof(unsigned short);
        return bf + wt + ints + 256;
    };
    int nb = (ws_size >= need(4)) ? 4 : 1;
    int npass = B / nb;
    int xg = 8 / nb;

    char* p = (char*)d_ws;
    unsigned short* fb  = (unsigned short*)p; p += (size_t)nb * N * 128 * sizeof(unsigned short);
    unsigned short* A1  = (unsigned short*)p; p += (size_t)nb * N * 128 * sizeof(unsigned short);
    unsigned short* H2b = (unsigned short*)p; p += (size_t)nb * N * 128 * sizeof(unsigned short);
    unsigned short* Wt1 = (unsigned short*)p; p += 32768 * sizeof(unsigned short);
    unsigned short* Wt2 = (unsigned short*)p; p += 32768 * sizeof(unsigned short);
    int* offs = (int*)p;  p += (size_t)nb * (N + 1) * sizeof(int);
    int* curs = (int*)p;  p += (size_t)nb * N * sizeof(int);
    unsigned short* elist = (unsigned short*)p;

    k_prep_w<<<128, 256, 0, stream>>>(W1, W2, Wt1, Wt2);

    const int nbx = (N + 31) / 32;                 // node-blocks per pass
    const int jpbE = (E + 255) / 256;              // edge chunks per batch
    dim3 gEdge(8 * ((jpbE + xg - 1) / xg), 1, 1);
    dim3 gAgg(8 * ((2 * nbx + xg - 1) / xg), 1, 1);

    for (int pass = 0; pass < npass; pass++) {
        int b0 = pass * nb;
        const float* feat_p = features + (size_t)b0 * N * 128;
        const int* src_p = src + (size_t)b0 * E;
        const int* dst_p = dst + (size_t)b0 * E;
        float* out_p = out + (size_t)b0 * N * 128;

        hipMemsetAsync(curs, 0, (size_t)nb * N * sizeof(int), stream);

        // features -> bf16 (streaming)
        long n8 = (long)nb * N * 128 / 8;
        k_tobf<<<(int)((n8 + 255) / 256), 256, 0, stream>>>(feat_p, fb, n8);

        k_count<<<gEdge, 256, 0, stream>>>(dst_p, E, curs, N, E, nb, jpbE);
        k_scan<<<dim3(1, 1, nb), 1024, 0, stream>>>(curs, N, offs, N + 1, curs, N, N);
        k_fill<<<gEdge, 256, 0, stream>>>(src_p, E, dst_p, E, curs, N, elist, E, E, nb, jpbE);

        // conv1 aggregation (bf16 gather) -> single bf16 A1
        k_agg<true><<<gAgg, 256, 0, stream>>>(fb, (long)N * 128, offs, N + 1,
                                              elist, E, nullptr, A1, (long)N * 128,
                                              N, nb, nbx);
        // FUSED: H2b = bf16( relu(A1@W1+b1) @ W2 )
        k_mlp<<<dim3((N + 63) / 64, 1, nb), 256, 0, stream>>>(
            A1, (long)N * 128, Wt1, Wt2, b1, H2b, (long)N * 128, N);
        // conv2 aggregation (bf16 gather) + bias: out = segsum(H2b[src] -> dst) + b2
        k_agg<false><<<gAgg, 256, 0, stream>>>(H2b, (long)N * 128, offs, N + 1,
                                               elist, E, b2, out_p, (long)N * 128,
                                               N, nb, nbx);
    }
}

// Round 14
// 264.144 us; speedup vs baseline: 1.5910x; 1.1738x over previous
//
#include <hip/hip_runtime.h>

#define NN 20000   // nodes per graph

typedef __attribute__((ext_vector_type(8))) __bf16 bf16x8;
typedef __attribute__((ext_vector_type(8))) unsigned short ushort8;
typedef __attribute__((ext_vector_type(4))) float f32x4;

__device__ __forceinline__ unsigned short f2bf(float f) {
    unsigned u = __builtin_bit_cast(unsigned, f);
    u += 0x7fff + ((u >> 16) & 1);   // round-to-nearest-even
    return (unsigned short)(u >> 16);
}
__device__ __forceinline__ float bf2f(unsigned short h) {
    unsigned u = ((unsigned)h) << 16;
    return __builtin_bit_cast(float, u);
}

// ---------------- fp32 -> bf16 streaming convert ----------------

__global__ void k_tobf(const float* __restrict__ in, unsigned short* __restrict__ outp,
                       long n8) {
    long i = (long)blockIdx.x * 256 + threadIdx.x;
    if (i >= n8) return;
    const float4* s = (const float4*)(in + i * 8);
    float4 v0 = s[0], v1 = s[1];
    ushort8 r;
    r[0] = f2bf(v0.x); r[1] = f2bf(v0.y); r[2] = f2bf(v0.z); r[3] = f2bf(v0.w);
    r[4] = f2bf(v1.x); r[5] = f2bf(v1.y); r[6] = f2bf(v1.z); r[7] = f2bf(v1.w);
    *(ushort8*)(outp + i * 8) = r;
}

// ---------------- CSR build (XCD-affine: batch = (gid&7)%nb) ----------------

__global__ void k_count(const int* __restrict__ dst, long dst_bs,
                        int* __restrict__ counts, long cnt_bs, int E, int nb, int jpb) {
    int gid = blockIdx.x;
    int xcd = gid & 7;
    int b = xcd % nb;
    int xg = 8 / nb;
    int jj = (gid >> 3) * xg + (xcd / nb);
    if (jj >= jpb) return;
    int e = jj * 256 + threadIdx.x;
    if (e < E)
        atomicAdd(&counts[(size_t)b * cnt_bs + dst[(size_t)b * dst_bs + e]], 1);
}

// one 1024-thread block per batch: exclusive scan of counts -> offs, cursor
__global__ void k_scan(const int* __restrict__ counts, long cnt_bs,
                       int* __restrict__ offs, long off_bs,
                       int* __restrict__ cursor, long cur_bs, int n) {
    int b = blockIdx.z;
    const int* cnt = counts + (size_t)b * cnt_bs;
    int* off = offs + (size_t)b * off_bs;
    int* cur = cursor + (size_t)b * cur_bs;
    __shared__ int sums[1024];
    int t = threadIdx.x;
    int chunk = (n + 1023) / 1024;
    int lo = t * chunk;
    int hi = min(lo + chunk, n);
    int s = 0;
    for (int i = lo; i < hi; i++) s += cnt[i];
    sums[t] = s;
    __syncthreads();
    for (int d2 = 1; d2 < 1024; d2 <<= 1) {
        int x = (t >= d2) ? sums[t - d2] : 0;
        __syncthreads();
        sums[t] += x;
        __syncthreads();
    }
    if (t == 1023) off[n] = sums[1023];
    int run = sums[t] - s;
    for (int i = lo; i < hi; i++) {
        int c = cnt[i];
        off[i] = run;
        cur[i] = run;
        run += c;
    }
}

__global__ void k_fill(const int* __restrict__ src, long src_bs,
                       const int* __restrict__ dst, long dst_bs,
                       int* __restrict__ cursor, long cur_bs,
                       unsigned short* __restrict__ elist, long el_bs,
                       int E, int nb, int jpb) {
    int gid = blockIdx.x;
    int xcd = gid & 7;
    int b = xcd % nb;
    int xg = 8 / nb;
    int jj = (gid >> 3) * xg + (xcd / nb);
    if (jj >= jpb) return;
    int e = jj * 256 + threadIdx.x;
    if (e < E) {
        int d = dst[(size_t)b * dst_bs + e];
        int s = src[(size_t)b * src_bs + e];
        int p = atomicAdd(&cursor[(size_t)b * cur_bs + d], 1);
        elist[(size_t)b * el_bs + p] = (unsigned short)s;
    }
}

// ---------------- bf16 aggregation: 64-col strips, XCD-affine batches ----------------
// BFOUT: write single bf16 (no bias); else fp32 + bias.

template <bool BFOUT>
__global__ void k_agg(const unsigned short* __restrict__ feat, long feat_bs,
                      const int* __restrict__ offs, long off_bs,
                      const unsigned short* __restrict__ elist, long el_bs,
                      const float* __restrict__ bias,   // nullable
                      void* __restrict__ o1,
                      long out_bs, int N, int nb, int nbx) {
    int gid = blockIdx.x;
    int xcd = gid & 7;
    int b = xcd % nb;
    int xg = 8 / nb;
    int jj = (gid >> 3) * xg + (xcd / nb);
    if (jj >= 2 * nbx) return;
    int pass = (jj >= nbx) ? 1 : 0;
    int nbk = jj - pass * nbx;
    int g = threadIdx.x >> 3;        // 32 node-groups per block
    int lane = threadIdx.x & 7;
    int n = nbk * 32 + g;
    if (n >= N) return;
    int col0 = pass * 64 + lane * 8;
    const unsigned short* fp = feat + (size_t)b * feat_bs + col0;
    const int* off = offs + (size_t)b * off_bs;
    const unsigned short* el = elist + (size_t)b * el_bs;
    int lo = off[n], hi = off[n + 1];
    float a0[8] = {}, a1[8] = {}, a2[8] = {}, a3[8] = {};
    auto acc = [&](float* a, ushort8 v) {
#pragma unroll
        for (int i = 0; i < 8; i++) a[i] += bf2f(v[i]);
    };
    int e = lo;
    for (; e < hi && (e & 3); e++)
        acc(a0, *(const ushort8*)&fp[(size_t)el[e] * 128]);
    for (; e + 4 <= hi; e += 4) {
        ushort4 idx = *(const ushort4*)&el[e];
        ushort8 v0 = *(const ushort8*)&fp[(size_t)idx.x * 128];
        ushort8 v1 = *(const ushort8*)&fp[(size_t)idx.y * 128];
        ushort8 v2 = *(const ushort8*)&fp[(size_t)idx.z * 128];
        ushort8 v3 = *(const ushort8*)&fp[(size_t)idx.w * 128];
        acc(a0, v0); acc(a1, v1); acc(a2, v2); acc(a3, v3);
    }
    for (; e < hi; e++)
        acc(a0, *(const ushort8*)&fp[(size_t)el[e] * 128]);
    float r[8];
#pragma unroll
    for (int i = 0; i < 8; i++) r[i] = (a0[i] + a1[i]) + (a2[i] + a3[i]);
    size_t oi = (size_t)b * out_bs + (size_t)n * 128 + col0;
    if (BFOUT) {
        ushort8 qh;
#pragma unroll
        for (int i = 0; i < 8; i++) qh[i] = f2bf(r[i]);
        *(ushort8*)((unsigned short*)o1 + oi) = qh;
    } else {
        float* op = (float*)o1 + oi;
        const float* bp = bias + col0;
#pragma unroll
        for (int i = 0; i < 8; i++) r[i] += bp[i];
        *(float4*)(op) = make_float4(r[0], r[1], r[2], r[3]);
        *(float4*)(op + 4) = make_float4(r[4], r[5], r[6], r[7]);
    }
}

// ---------------- W prep: fp32 [K][N] -> transposed bf16 [N][K] ----------------

__global__ void k_prep_w(const float* __restrict__ W1, const float* __restrict__ W2,
                         unsigned short* __restrict__ Wt1, unsigned short* __restrict__ Wt2) {
    int i = blockIdx.x * 256 + threadIdx.x;
    if (i < 128 * 256) {
        {   // W1 [128][256] -> Wt1 [256][128]
            int k = i / 256, n = i % 256;
            Wt1[n * 128 + k] = f2bf(W1[i]);
        }
        {   // W2 [256][128] -> Wt2 [128][256]
            int k = i / 128, n = i % 128;
            Wt2[n * 256 + k] = f2bf(W2[i]);
        }
    }
}

// ---------------- FUSED MLP, W-register-resident, A-streaming ----------------
// Block = 16 rows x all cols; wave w owns W1 cols [w*64,w*64+64) (64 VGPR) and
// W2 cols [w*32,w*32+32) (64 VGPR), loaded ONCE. Grid-strides over row-tiles:
// phase A -> H[16][256] in LDS (swizzled) -> barrier -> phase B (acc in reg)
// -> H2 stage (separate LDS) -> barrier -> coalesced writeback.

__launch_bounds__(256, 2)
__global__ void k_mlp(const unsigned short* __restrict__ A1, long A_bs,
                      const unsigned short* __restrict__ Wt1,
                      const unsigned short* __restrict__ Wt2,
                      const float* __restrict__ b1,
                      unsigned short* __restrict__ H2b, long C_bs,
                      int M, int ntiles) {
    __shared__ unsigned short HH[16 * 256];    // 8 KB H tile
    __shared__ unsigned short H2S[16 * 128];   // 4 KB H2 stage
    char* HHc = (char*)HH;
    char* H2c = (char*)H2S;
    int b = blockIdx.z;
    int w = threadIdx.x >> 6, lane = threadIdx.x & 63;
    int colg = lane & 15, kg = lane >> 4;

    // ---- resident W slices (loaded once) ----
    bf16x8 w1f[4][4];   // [c][ks]: W1 col w*64 + c*16 + colg, k = ks*32 + kg*8
#pragma unroll
    for (int c = 0; c < 4; c++) {
        const unsigned short* ph = Wt1 + (size_t)(w * 64 + c * 16 + colg) * 128 + kg * 8;
#pragma unroll
        for (int ks = 0; ks < 4; ks++) w1f[c][ks] = *(const bf16x8*)(ph + ks * 32);
    }
    bf16x8 w2f[2][8];   // [c][ks2]: W2 col w*32 + c*16 + colg, k = ks2*32 + kg*8
#pragma unroll
    for (int c = 0; c < 2; c++) {
        const unsigned short* ph = Wt2 + (size_t)(w * 32 + c * 16 + colg) * 256 + kg * 8;
#pragma unroll
        for (int ks = 0; ks < 8; ks++) w2f[c][ks] = *(const bf16x8*)(ph + ks * 32);
    }
    // bias slice for this wave's H cols
    float4 bv[4];
#pragma unroll
    for (int c = 0; c < 4; c++) bv[c] = *(const float4*)&b1[w * 64 + c * 16 + kg * 4];

    for (int t = blockIdx.x; t < ntiles; t += gridDim.x) {
        int row = t * 16 + colg;
        int rc = (row < M) ? row : M - 1;
        const unsigned short* pa = A1 + (size_t)b * A_bs + (size_t)rc * 128 + kg * 8;
        bf16x8 fa[4];
#pragma unroll
        for (int ks = 0; ks < 4; ks++) fa[ks] = *(const bf16x8*)(pa + ks * 32);

        // ---- phase A: H[16][w*64 .. w*64+64) -> LDS ----
#pragma unroll
        for (int c = 0; c < 4; c++) {
            f32x4 a = (f32x4){0.f, 0.f, 0.f, 0.f};
#pragma unroll
            for (int ks = 0; ks < 4; ks++)
                a = __builtin_amdgcn_mfma_f32_16x16x32_bf16(w1f[c][ks], fa[ks], a, 0, 0, 0);
            float v[4] = {a[0] + bv[c].x, a[1] + bv[c].y, a[2] + bv[c].z, a[3] + bv[c].w};
#pragma unroll
            for (int j = 0; j < 4; j++) v[j] = fmaxf(v[j], 0.f);
            union { unsigned short u[4]; uint2 q; } qh;
#pragma unroll
            for (int j = 0; j < 4; j++) qh.u[j] = f2bf(v[j]);
            // row = colg (D col=lane&15), cols w*64 + c*16 + kg*4
            int off = (colg * 512 + w * 128 + c * 32 + kg * 8) ^ ((colg & 7) << 4);
            *(uint2*)(HHc + off) = qh.q;
        }
        __syncthreads();

        // ---- phase B: H2[16][w*32 .. w*32+32) += H @ W2-slice ----
        f32x4 a2[2];
        a2[0] = (f32x4){0.f, 0.f, 0.f, 0.f};
        a2[1] = (f32x4){0.f, 0.f, 0.f, 0.f};
#pragma unroll
        for (int ks2 = 0; ks2 < 8; ks2++) {
            int roff = (colg * 512 + ks2 * 64 + kg * 16) ^ ((colg & 7) << 4);
            bf16x8 fh = *(const bf16x8*)(HHc + roff);
            a2[0] = __builtin_amdgcn_mfma_f32_16x16x32_bf16(w2f[0][ks2], fh, a2[0], 0, 0, 0);
            a2[1] = __builtin_amdgcn_mfma_f32_16x16x32_bf16(w2f[1][ks2], fh, a2[1], 0, 0, 0);
        }
        // stage H2 (separate LDS region; no race with HH readers)
#pragma unroll
        for (int c = 0; c < 2; c++) {
            union { unsigned short u[4]; uint2 q; } qh;
#pragma unroll
            for (int j = 0; j < 4; j++) qh.u[j] = f2bf(a2[c][j]);
            int off = (colg * 256 + w * 64 + c * 32 + kg * 8) ^ ((colg & 7) << 4);
            *(uint2*)(H2c + off) = qh.q;
        }
        __syncthreads();

        // ---- coalesced writeback: 16 rows x 128 cols bf16 = 256 uint4 ----
        {
            int idx = threadIdx.x;
            int r2 = idx >> 4;
            int u4 = idx & 15;
            int off = (r2 * 256 + u4 * 16) ^ ((r2 & 7) << 4);
            int grow = t * 16 + r2;
            if (grow < M) {
                uint4 v = *(const uint4*)(H2c + off);
                *(uint4*)(H2b + (size_t)b * C_bs + (size_t)grow * 128 + u4 * 8) = v;
            }
        }
    }
}

// ---------------- host ----------------

extern "C" void kernel_launch(void* const* d_in, const int* in_sizes, int n_in,
                              void* d_out, int out_size, void* d_ws, size_t ws_size,
                              hipStream_t stream) {
    const float* features = (const float*)d_in[0];  // [B,N,128]
    const int* src = (const int*)d_in[1];           // [B,E]
    const int* dst = (const int*)d_in[2];           // [B,E]
    const float* W1 = (const float*)d_in[3];        // [128,256]
    const float* b1 = (const float*)d_in[4];        // [256]
    const float* W2 = (const float*)d_in[5];        // [256,128]
    const float* b2 = (const float*)d_in[6];        // [128]
    float* out = (float*)d_out;                     // [B,N,128]

    const int B = 4;
    const int N = NN;
    const int E = in_sizes[1] / B;

    auto need = [&](int nb) -> size_t {
        size_t bf = ((size_t)nb * N * (128 + 128 + 128)) * sizeof(unsigned short);
        size_t wt = 2 * 32768 * sizeof(unsigned short);
        size_t ints = (size_t)nb * ((size_t)(N + 1) + N) * sizeof(int)
                    + (size_t)nb * E * sizeof(unsigned short);
        return bf + wt + ints + 256;
    };
    int nb = (ws_size >= need(4)) ? 4 : 1;
    int npass = B / nb;
    int xg = 8 / nb;

    char* p = (char*)d_ws;
    unsigned short* fb  = (unsigned short*)p; p += (size_t)nb * N * 128 * sizeof(unsigned short);
    unsigned short* A1  = (unsigned short*)p; p += (size_t)nb * N * 128 * sizeof(unsigned short);
    unsigned short* H2b = (unsigned short*)p; p += (size_t)nb * N * 128 * sizeof(unsigned short);
    unsigned short* Wt1 = (unsigned short*)p; p += 32768 * sizeof(unsigned short);
    unsigned short* Wt2 = (unsigned short*)p; p += 32768 * sizeof(unsigned short);
    int* offs = (int*)p;  p += (size_t)nb * (N + 1) * sizeof(int);
    int* curs = (int*)p;  p += (size_t)nb * N * sizeof(int);
    unsigned short* elist = (unsigned short*)p;

    k_prep_w<<<128, 256, 0, stream>>>(W1, W2, Wt1, Wt2);

    const int nbx = (N + 31) / 32;                 // node-blocks per pass
    const int jpbE = (E + 255) / 256;              // edge chunks per batch
    const int ntiles = (N + 15) / 16;              // 16-row tiles per batch
    dim3 gEdge(8 * ((jpbE + xg - 1) / xg), 1, 1);
    dim3 gAgg(8 * ((2 * nbx + xg - 1) / xg), 1, 1);

    for (int pass = 0; pass < npass; pass++) {
        int b0 = pass * nb;
        const float* feat_p = features + (size_t)b0 * N * 128;
        const int* src_p = src + (size_t)b0 * E;
        const int* dst_p = dst + (size_t)b0 * E;
        float* out_p = out + (size_t)b0 * N * 128;

        hipMemsetAsync(curs, 0, (size_t)nb * N * sizeof(int), stream);

        // features -> bf16 (streaming)
        long n8 = (long)nb * N * 128 / 8;
        k_tobf<<<(int)((n8 + 255) / 256), 256, 0, stream>>>(feat_p, fb, n8);

        k_count<<<gEdge, 256, 0, stream>>>(dst_p, E, curs, N, E, nb, jpbE);
        k_scan<<<dim3(1, 1, nb), 1024, 0, stream>>>(curs, N, offs, N + 1, curs, N, N);
        k_fill<<<gEdge, 256, 0, stream>>>(src_p, E, dst_p, E, curs, N, elist, E, E, nb, jpbE);

        // conv1 aggregation (bf16 gather) -> single bf16 A1
        k_agg<true><<<gAgg, 256, 0, stream>>>(fb, (long)N * 128, offs, N + 1,
                                              elist, E, nullptr, A1, (long)N * 128,
                                              N, nb, nbx);
        // FUSED: H2b = bf16( relu(A1@W1+b1) @ W2 )   (W register-resident)
        k_mlp<<<dim3(250, 1, nb), 256, 0, stream>>>(
            A1, (long)N * 128, Wt1, Wt2, b1, H2b, (long)N * 128, N, ntiles);
        // conv2 aggregation (bf16 gather) + bias: out = segsum(H2b[src] -> dst) + b2
        k_agg<false><<<gAgg, 256, 0, stream>>>(H2b, (long)N * 128, offs, N + 1,
                                               elist, E, b2, out_p, (long)N * 128,
                                               N, nb, nbx);
    }
}

// Round 15
// 259.324 us; speedup vs baseline: 1.6206x; 1.0186x over previous
//
#include <hip/hip_runtime.h>

#define NN 20000   // nodes per graph

typedef __attribute__((ext_vector_type(8))) __bf16 bf16x8;
typedef __attribute__((ext_vector_type(8))) unsigned short ushort8;
typedef __attribute__((ext_vector_type(4))) float f32x4;

__device__ __forceinline__ unsigned short f2bf(float f) {
    unsigned u = __builtin_bit_cast(unsigned, f);
    u += 0x7fff + ((u >> 16) & 1);   // round-to-nearest-even
    return (unsigned short)(u >> 16);
}
__device__ __forceinline__ float bf2f(unsigned short h) {
    unsigned u = ((unsigned)h) << 16;
    return __builtin_bit_cast(float, u);
}

// ---------------- fp32 -> bf16 streaming convert ----------------

__global__ void k_tobf(const float* __restrict__ in, unsigned short* __restrict__ outp,
                       long n8) {
    long i = (long)blockIdx.x * 256 + threadIdx.x;
    if (i >= n8) return;
    const float4* s = (const float4*)(in + i * 8);
    float4 v0 = s[0], v1 = s[1];
    ushort8 r;
    r[0] = f2bf(v0.x); r[1] = f2bf(v0.y); r[2] = f2bf(v0.z); r[3] = f2bf(v0.w);
    r[4] = f2bf(v1.x); r[5] = f2bf(v1.y); r[6] = f2bf(v1.z); r[7] = f2bf(v1.w);
    *(ushort8*)(outp + i * 8) = r;
}

// ---------------- CSR build ----------------
// XCD-affine + dst-half partition: xcd = gid&7; b = xcd%nb; grp = xcd/nb;
// half = grp&1 (dst range), sub = grp>>1. Each (batch,half) is owned by xh
// XCDs with an EXCLUSIVE cursor/elist range (no cross-L2 line migration).

__global__ void k_count(const int* __restrict__ dst, long dst_bs,
                        int* __restrict__ counts, long cnt_bs,
                        int E, int nb, int jpb, int Nhalf) {
    int gid = blockIdx.x;
    int xcd = gid & 7;
    int b = xcd % nb;
    int grp = xcd / nb;
    int half = grp & 1;
    int sub = grp >> 1;
    int xh = (8 / nb) >> 1;
    int jj = (gid >> 3) * xh + sub;
    if (jj >= jpb) return;
    int e = jj * 256 + threadIdx.x;
    if (e < E) {
        int d = dst[(size_t)b * dst_bs + e];
        if ((d >= Nhalf) == (half != 0))
            atomicAdd(&counts[(size_t)b * cnt_bs + d], 1);
    }
}

// one 1024-thread block per batch: exclusive scan of counts -> offs, cursor
__global__ void k_scan(const int* __restrict__ counts, long cnt_bs,
                       int* __restrict__ offs, long off_bs,
                       int* __restrict__ cursor, long cur_bs, int n) {
    int b = blockIdx.z;
    const int* cnt = counts + (size_t)b * cnt_bs;
    int* off = offs + (size_t)b * off_bs;
    int* cur = cursor + (size_t)b * cur_bs;
    __shared__ int sums[1024];
    int t = threadIdx.x;
    int chunk = (n + 1023) / 1024;
    int lo = t * chunk;
    int hi = min(lo + chunk, n);
    int s = 0;
    for (int i = lo; i < hi; i++) s += cnt[i];
    sums[t] = s;
    __syncthreads();
    for (int d2 = 1; d2 < 1024; d2 <<= 1) {
        int x = (t >= d2) ? sums[t - d2] : 0;
        __syncthreads();
        sums[t] += x;
        __syncthreads();
    }
    if (t == 1023) off[n] = sums[1023];
    int run = sums[t] - s;
    for (int i = lo; i < hi; i++) {
        int c = cnt[i];
        off[i] = run;
        cur[i] = run;
        run += c;
    }
}

__global__ void k_fill(const int* __restrict__ src, long src_bs,
                       const int* __restrict__ dst, long dst_bs,
                       int* __restrict__ cursor, long cur_bs,
                       unsigned short* __restrict__ elist, long el_bs,
                       int E, int nb, int jpb, int Nhalf) {
    int gid = blockIdx.x;
    int xcd = gid & 7;
    int b = xcd % nb;
    int grp = xcd / nb;
    int half = grp & 1;
    int sub = grp >> 1;
    int xh = (8 / nb) >> 1;
    int jj = (gid >> 3) * xh + sub;
    if (jj >= jpb) return;
    int e = jj * 256 + threadIdx.x;
    if (e < E) {
        int d = dst[(size_t)b * dst_bs + e];
        if ((d >= Nhalf) == (half != 0)) {
            int s = src[(size_t)b * src_bs + e];
            int p = atomicAdd(&cursor[(size_t)b * cur_bs + d], 1);
            elist[(size_t)b * el_bs + p] = (unsigned short)s;
        }
    }
}

// ---------------- bf16 aggregation: 64-col strips; pass = XCD-half ----------------
// Each (batch,pass) owned by xh XCDs: exclusive 1.28 MB half-strip per L2.
// BFOUT: write single bf16 (no bias); else fp32 + bias.

template <bool BFOUT>
__global__ void k_agg(const unsigned short* __restrict__ feat, long feat_bs,
                      const int* __restrict__ offs, long off_bs,
                      const unsigned short* __restrict__ elist, long el_bs,
                      const float* __restrict__ bias,   // nullable
                      void* __restrict__ o1,
                      long out_bs, int N, int nb, int nbx) {
    int gid = blockIdx.x;
    int xcd = gid & 7;
    int b = xcd % nb;
    int grp = xcd / nb;
    int pass = grp & 1;
    int sub = grp >> 1;
    int xh = (8 / nb) >> 1;
    int nbk = (gid >> 3) * xh + sub;
    if (nbk >= nbx) return;
    int g = threadIdx.x >> 3;        // 32 node-groups per block
    int lane = threadIdx.x & 7;
    int n = nbk * 32 + g;
    if (n >= N) return;
    int col0 = pass * 64 + lane * 8;
    const unsigned short* fp = feat + (size_t)b * feat_bs + col0;
    const int* off = offs + (size_t)b * off_bs;
    const unsigned short* el = elist + (size_t)b * el_bs;
    int lo = off[n], hi = off[n + 1];
    float a0[8] = {}, a1[8] = {}, a2[8] = {}, a3[8] = {};
    auto acc = [&](float* a, ushort8 v) {
#pragma unroll
        for (int i = 0; i < 8; i++) a[i] += bf2f(v[i]);
    };
    int e = lo;
    for (; e < hi && (e & 3); e++)
        acc(a0, *(const ushort8*)&fp[(size_t)el[e] * 128]);
    for (; e + 4 <= hi; e += 4) {
        ushort4 idx = *(const ushort4*)&el[e];
        ushort8 v0 = *(const ushort8*)&fp[(size_t)idx.x * 128];
        ushort8 v1 = *(const ushort8*)&fp[(size_t)idx.y * 128];
        ushort8 v2 = *(const ushort8*)&fp[(size_t)idx.z * 128];
        ushort8 v3 = *(const ushort8*)&fp[(size_t)idx.w * 128];
        acc(a0, v0); acc(a1, v1); acc(a2, v2); acc(a3, v3);
    }
    for (; e < hi; e++)
        acc(a0, *(const ushort8*)&fp[(size_t)el[e] * 128]);
    float r[8];
#pragma unroll
    for (int i = 0; i < 8; i++) r[i] = (a0[i] + a1[i]) + (a2[i] + a3[i]);
    size_t oi = (size_t)b * out_bs + (size_t)n * 128 + col0;
    if (BFOUT) {
        ushort8 qh;
#pragma unroll
        for (int i = 0; i < 8; i++) qh[i] = f2bf(r[i]);
        *(ushort8*)((unsigned short*)o1 + oi) = qh;
    } else {
        float* op = (float*)o1 + oi;
        const float* bp = bias + col0;
#pragma unroll
        for (int i = 0; i < 8; i++) r[i] += bp[i];
        *(float4*)(op) = make_float4(r[0], r[1], r[2], r[3]);
        *(float4*)(op + 4) = make_float4(r[4], r[5], r[6], r[7]);
    }
}

// ---------------- W prep: fp32 [K][N] -> transposed bf16 [N][K] ----------------

__global__ void k_prep_w(const float* __restrict__ W1, const float* __restrict__ W2,
                         unsigned short* __restrict__ Wt1, unsigned short* __restrict__ Wt2) {
    int i = blockIdx.x * 256 + threadIdx.x;
    if (i < 128 * 256) {
        {   // W1 [128][256] -> Wt1 [256][128]
            int k = i / 256, n = i % 256;
            Wt1[n * 128 + k] = f2bf(W1[i]);
        }
        {   // W2 [256][128] -> Wt2 [128][256]
            int k = i / 128, n = i % 128;
            Wt2[n * 256 + k] = f2bf(W2[i]);
        }
    }
}

// ---------------- FUSED MLP, W-register-resident, A-streaming ----------------
// Block = 16 rows x all cols; wave w owns W1 cols [w*64,w*64+64) (64 VGPR) and
// W2 cols [w*32,w*32+32) (64 VGPR), loaded ONCE. Grid-strides over row-tiles.

__launch_bounds__(256, 2)
__global__ void k_mlp(const unsigned short* __restrict__ A1, long A_bs,
                      const unsigned short* __restrict__ Wt1,
                      const unsigned short* __restrict__ Wt2,
                      const float* __restrict__ b1,
                      unsigned short* __restrict__ H2b, long C_bs,
                      int M, int ntiles) {
    __shared__ unsigned short HH[16 * 256];    // 8 KB H tile
    __shared__ unsigned short H2S[16 * 128];   // 4 KB H2 stage
    char* HHc = (char*)HH;
    char* H2c = (char*)H2S;
    int b = blockIdx.z;
    int w = threadIdx.x >> 6, lane = threadIdx.x & 63;
    int colg = lane & 15, kg = lane >> 4;

    // ---- resident W slices (loaded once) ----
    bf16x8 w1f[4][4];
#pragma unroll
    for (int c = 0; c < 4; c++) {
        const unsigned short* ph = Wt1 + (size_t)(w * 64 + c * 16 + colg) * 128 + kg * 8;
#pragma unroll
        for (int ks = 0; ks < 4; ks++) w1f[c][ks] = *(const bf16x8*)(ph + ks * 32);
    }
    bf16x8 w2f[2][8];
#pragma unroll
    for (int c = 0; c < 2; c++) {
        const unsigned short* ph = Wt2 + (size_t)(w * 32 + c * 16 + colg) * 256 + kg * 8;
#pragma unroll
        for (int ks = 0; ks < 8; ks++) w2f[c][ks] = *(const bf16x8*)(ph + ks * 32);
    }
    float4 bv[4];
#pragma unroll
    for (int c = 0; c < 4; c++) bv[c] = *(const float4*)&b1[w * 64 + c * 16 + kg * 4];

    for (int t = blockIdx.x; t < ntiles; t += gridDim.x) {
        int row = t * 16 + colg;
        int rc = (row < M) ? row : M - 1;
        const unsigned short* pa = A1 + (size_t)b * A_bs + (size_t)rc * 128 + kg * 8;
        bf16x8 fa[4];
#pragma unroll
        for (int ks = 0; ks < 4; ks++) fa[ks] = *(const bf16x8*)(pa + ks * 32);

        // ---- phase A: H[16][w*64 .. w*64+64) -> LDS ----
#pragma unroll
        for (int c = 0; c < 4; c++) {
            f32x4 a = (f32x4){0.f, 0.f, 0.f, 0.f};
#pragma unroll
            for (int ks = 0; ks < 4; ks++)
                a = __builtin_amdgcn_mfma_f32_16x16x32_bf16(w1f[c][ks], fa[ks], a, 0, 0, 0);
            float v[4] = {a[0] + bv[c].x, a[1] + bv[c].y, a[2] + bv[c].z, a[3] + bv[c].w};
#pragma unroll
            for (int j = 0; j < 4; j++) v[j] = fmaxf(v[j], 0.f);
            union { unsigned short u[4]; uint2 q; } qh;
#pragma unroll
            for (int j = 0; j < 4; j++) qh.u[j] = f2bf(v[j]);
            int off = (colg * 512 + w * 128 + c * 32 + kg * 8) ^ ((colg & 7) << 4);
            *(uint2*)(HHc + off) = qh.q;
        }
        __syncthreads();

        // ---- phase B: H2[16][w*32 .. w*32+32) += H @ W2-slice ----
        f32x4 a2[2];
        a2[0] = (f32x4){0.f, 0.f, 0.f, 0.f};
        a2[1] = (f32x4){0.f, 0.f, 0.f, 0.f};
#pragma unroll
        for (int ks2 = 0; ks2 < 8; ks2++) {
            int roff = (colg * 512 + ks2 * 64 + kg * 16) ^ ((colg & 7) << 4);
            bf16x8 fh = *(const bf16x8*)(HHc + roff);
            a2[0] = __builtin_amdgcn_mfma_f32_16x16x32_bf16(w2f[0][ks2], fh, a2[0], 0, 0, 0);
            a2[1] = __builtin_amdgcn_mfma_f32_16x16x32_bf16(w2f[1][ks2], fh, a2[1], 0, 0, 0);
        }
#pragma unroll
        for (int c = 0; c < 2; c++) {
            union { unsigned short u[4]; uint2 q; } qh;
#pragma unroll
            for (int j = 0; j < 4; j++) qh.u[j] = f2bf(a2[c][j]);
            int off = (colg * 256 + w * 64 + c * 32 + kg * 8) ^ ((colg & 7) << 4);
            *(uint2*)(H2c + off) = qh.q;
        }
        __syncthreads();

        // ---- coalesced writeback: 16 rows x 128 cols bf16 = 256 uint4 ----
        {
            int idx = threadIdx.x;
            int r2 = idx >> 4;
            int u4 = idx & 15;
            int off = (r2 * 256 + u4 * 16) ^ ((r2 & 7) << 4);
            int grow = t * 16 + r2;
            if (grow < M) {
                uint4 v = *(const uint4*)(H2c + off);
                *(uint4*)(H2b + (size_t)b * C_bs + (size_t)grow * 128 + u4 * 8) = v;
            }
        }
    }
}

// ---------------- host ----------------

extern "C" void kernel_launch(void* const* d_in, const int* in_sizes, int n_in,
                              void* d_out, int out_size, void* d_ws, size_t ws_size,
                              hipStream_t stream) {
    const float* features = (const float*)d_in[0];  // [B,N,128]
    const int* src = (const int*)d_in[1];           // [B,E]
    const int* dst = (const int*)d_in[2];           // [B,E]
    const float* W1 = (const float*)d_in[3];        // [128,256]
    const float* b1 = (const float*)d_in[4];        // [256]
    const float* W2 = (const float*)d_in[5];        // [256,128]
    const float* b2 = (const float*)d_in[6];        // [128]
    float* out = (float*)d_out;                     // [B,N,128]

    const int B = 4;
    const int N = NN;
    const int E = in_sizes[1] / B;
    const int Nhalf = N / 2;

    auto need = [&](int nb) -> size_t {
        size_t bf = ((size_t)nb * N * (128 + 128 + 128)) * sizeof(unsigned short);
        size_t wt = 2 * 32768 * sizeof(unsigned short);
        size_t ints = (size_t)nb * ((size_t)(N + 1) + N) * sizeof(int)
                    + (size_t)nb * E * sizeof(unsigned short);
        return bf + wt + ints + 256;
    };
    int nb = (ws_size >= need(4)) ? 4 : 1;
    int npass = B / nb;
    int xh = (8 / nb) >> 1;                        // XCDs per (batch,half)

    char* p = (char*)d_ws;
    unsigned short* fb  = (unsigned short*)p; p += (size_t)nb * N * 128 * sizeof(unsigned short);
    unsigned short* A1  = (unsigned short*)p; p += (size_t)nb * N * 128 * sizeof(unsigned short);
    unsigned short* H2b = (unsigned short*)p; p += (size_t)nb * N * 128 * sizeof(unsigned short);
    unsigned short* Wt1 = (unsigned short*)p; p += 32768 * sizeof(unsigned short);
    unsigned short* Wt2 = (unsigned short*)p; p += 32768 * sizeof(unsigned short);
    int* offs = (int*)p;  p += (size_t)nb * (N + 1) * sizeof(int);
    int* curs = (int*)p;  p += (size_t)nb * N * sizeof(int);
    unsigned short* elist = (unsigned short*)p;

    k_prep_w<<<128, 256, 0, stream>>>(W1, W2, Wt1, Wt2);

    const int nbx = (N + 31) / 32;                 // node-blocks per pass
    const int jpbE = (E + 255) / 256;              // edge chunks per batch
    const int ntiles = (N + 15) / 16;              // 16-row tiles per batch
    dim3 gEdge(8 * ((jpbE + xh - 1) / xh), 1, 1);
    dim3 gAgg(8 * ((nbx + xh - 1) / xh), 1, 1);

    for (int pass = 0; pass < npass; pass++) {
        int b0 = pass * nb;
        const float* feat_p = features + (size_t)b0 * N * 128;
        const int* src_p = src + (size_t)b0 * E;
        const int* dst_p = dst + (size_t)b0 * E;
        float* out_p = out + (size_t)b0 * N * 128;

        hipMemsetAsync(curs, 0, (size_t)nb * N * sizeof(int), stream);

        // features -> bf16 (streaming)
        long n8 = (long)nb * N * 128 / 8;
        k_tobf<<<(int)((n8 + 255) / 256), 256, 0, stream>>>(feat_p, fb, n8);

        k_count<<<gEdge, 256, 0, stream>>>(dst_p, E, curs, N, E, nb, jpbE, Nhalf);
        k_scan<<<dim3(1, 1, nb), 1024, 0, stream>>>(curs, N, offs, N + 1, curs, N, N);
        k_fill<<<gEdge, 256, 0, stream>>>(src_p, E, dst_p, E, curs, N, elist, E,
                                          E, nb, jpbE, Nhalf);

        // conv1 aggregation (bf16 gather) -> single bf16 A1
        k_agg<true><<<gAgg, 256, 0, stream>>>(fb, (long)N * 128, offs, N + 1,
                                              elist, E, nullptr, A1, (long)N * 128,
                                              N, nb, nbx);
        // FUSED: H2b = bf16( relu(A1@W1+b1) @ W2 )   (W register-resident)
        k_mlp<<<dim3(250, 1, nb), 256, 0, stream>>>(
            A1, (long)N * 128, Wt1, Wt2, b1, H2b, (long)N * 128, N, ntiles);
        // conv2 aggregation (bf16 gather) + bias: out = segsum(H2b[src] -> dst) + b2
        k_agg<false><<<gAgg, 256, 0, stream>>>(H2b, (long)N * 128, offs, N + 1,
                                               elist, E, b2, out_p, (long)N * 128,
                                               N, nb, nbx);
    }
}